// Round 1
// baseline (32.320 us; speedup 1.0000x reference)
//
#include <hip/hip_runtime.h>

// DiffusionInitializer: out = P*noise + (1-P)*(latent @ W + b), P = prod(t/steps)
// Closed form of the 50-step scan (each step is a convex combination, so the
// noise/target weights always sum to 1; P = steps!/steps^steps ~ 3.5e-21).
//
// Memory-bound: latent is 16*2048*1024*4B = 128 MiB; floor ~21 us @ 6.3 TB/s.
// Decomposition: one wave (64 lanes) per output row; lane l owns d-slice
// {j*256 + l*4 + k : j<4, k<4} so its 48 W coefficients are loaded once into
// registers and reused across the wave's grid-stride rows. Latent reads are
// float4 with wave-contiguous 1KiB segments.

#define D_DIM 1024
#define NCHUNK (D_DIM / 256)  // float4-chunks of 64 lanes each

__launch_bounds__(256, 4)
__global__ void diffusion_init_kernel(const float* __restrict__ latent,
                                      const float* __restrict__ W,
                                      const float* __restrict__ bias,
                                      const float* __restrict__ noise,
                                      const int* __restrict__ steps_p,
                                      float* __restrict__ out,
                                      int rows) {
    const int lane   = threadIdx.x & 63;
    const int wid    = (blockIdx.x * blockDim.x + threadIdx.x) >> 6;
    const int nwaves = (gridDim.x * blockDim.x) >> 6;

    // steps scalar: robust to int32 vs float32 encoding of the Python scalar
    int steps = steps_p[0];
    if (steps <= 0 || steps > (1 << 20)) {
        float fs = __int_as_float(steps);
        if (fs >= 1.0f && fs < 1.0e6f) steps = (int)(fs + 0.5f);
        else steps = 50;
    }
    double pd = 1.0;
    for (int t = 1; t <= steps; ++t) pd *= (double)t / (double)steps;
    const float P   = (float)pd;
    const float omP = (float)(1.0 - pd);

    // Per-lane W fragment: chunk j covers d = j*256 + lane*4 + k, cols c=0..2.
    // W rows for d..d+3 are 12 consecutive floats at float-offset j*768+lane*12
    // (16B-aligned since lane*48B) -> 3x float4 per chunk.
    float wv[NCHUNK][12];
    const float4* W4 = (const float4*)W;
    #pragma unroll
    for (int j = 0; j < NCHUNK; ++j) {
        #pragma unroll
        for (int q = 0; q < 3; ++q) {
            float4 t = W4[j * 192 + lane * 3 + q];
            wv[j][q * 4 + 0] = t.x;
            wv[j][q * 4 + 1] = t.y;
            wv[j][q * 4 + 2] = t.z;
            wv[j][q * 4 + 3] = t.w;
        }
    }
    const float b0 = bias[0], b1 = bias[1], b2 = bias[2];

    const float4* L4 = (const float4*)latent;
    for (int row = wid; row < rows; row += nwaves) {
        float a0 = 0.f, a1 = 0.f, a2 = 0.f;
        const size_t rb = (size_t)row * (D_DIM / 4);
        #pragma unroll
        for (int j = 0; j < NCHUNK; ++j) {
            float4 v = L4[rb + j * 64 + lane];
            a0 = fmaf(v.x, wv[j][0], a0);
            a1 = fmaf(v.x, wv[j][1], a1);
            a2 = fmaf(v.x, wv[j][2], a2);
            a0 = fmaf(v.y, wv[j][3], a0);
            a1 = fmaf(v.y, wv[j][4], a1);
            a2 = fmaf(v.y, wv[j][5], a2);
            a0 = fmaf(v.z, wv[j][6], a0);
            a1 = fmaf(v.z, wv[j][7], a1);
            a2 = fmaf(v.z, wv[j][8], a2);
            a0 = fmaf(v.w, wv[j][9], a0);
            a1 = fmaf(v.w, wv[j][10], a1);
            a2 = fmaf(v.w, wv[j][11], a2);
        }
        // 64-lane butterfly reduction of the 3 accumulators
        #pragma unroll
        for (int off = 32; off > 0; off >>= 1) {
            a0 += __shfl_xor(a0, off, 64);
            a1 += __shfl_xor(a1, off, 64);
            a2 += __shfl_xor(a2, off, 64);
        }
        if (lane == 0) {
            const size_t o = (size_t)row * 3;
            out[o + 0] = omP * (a0 + b0) + P * noise[o + 0];
            out[o + 1] = omP * (a1 + b1) + P * noise[o + 1];
            out[o + 2] = omP * (a2 + b2) + P * noise[o + 2];
        }
    }
}

extern "C" void kernel_launch(void* const* d_in, const int* in_sizes, int n_in,
                              void* d_out, int out_size, void* d_ws, size_t ws_size,
                              hipStream_t stream) {
    const float* latent = (const float*)d_in[0];
    const float* W      = (const float*)d_in[1];
    const float* bias   = (const float*)d_in[2];
    const float* noise  = (const float*)d_in[3];
    const int*   steps  = (const int*)d_in[4];
    float* out = (float*)d_out;

    const int rows = in_sizes[3] / 3;  // B*S

    // 2048 blocks x 4 waves = 8192 waves -> 4 rows per wave at B*S=32768
    const int blocks = 2048;
    diffusion_init_kernel<<<blocks, 256, 0, stream>>>(latent, W, bias, noise,
                                                      steps, out, rows);
}

// Round 2
// 31.493 us; speedup vs baseline: 1.0262x; 1.0262x over previous
//
#include <hip/hip_runtime.h>

// DiffusionInitializer: out = P*noise + (1-P)*(latent @ W + b), P = prod(t/steps)
// Closed form of the 50-step scan (each step is a convex combination; the
// noise/target weights sum to 1; P = steps!/steps^steps ~ 3.5e-21).
//
// Memory-bound: latent = 128 MiB fp32; floor ~19 us at the measured 7.1 TB/s
// achievable (harness fill kernels). R1 was 32.3 us; this round removes the
// f64 P-prologue (50 dependent f64 divides/wave -> ~200cy of __log2f) and
// batches 4 rows per wave: 16 float4 loads issued up front (16 KB MLP/wave),
// 12 independent FMA chains, 12 independent butterfly-reduce chains, and a
// 48B-contiguous store from lanes 0-3.

#define D_DIM 1024
#define NCHUNK (D_DIM / 256)   // float4-chunks of 64 lanes each = 4
#define RPW 4                  // rows per wave

__launch_bounds__(256, 3)
__global__ void diffusion_init_kernel(const float* __restrict__ latent,
                                      const float* __restrict__ W,
                                      const float* __restrict__ bias,
                                      const float* __restrict__ noise,
                                      const int* __restrict__ steps_p,
                                      float* __restrict__ out,
                                      int rows) {
    const int lane   = threadIdx.x & 63;
    const int wid    = (blockIdx.x * blockDim.x + threadIdx.x) >> 6;
    const int nwaves = (gridDim.x * blockDim.x) >> 6;

    // Per-lane W fragment: chunk j covers d = j*256 + lane*4 + k, cols c=0..2.
    // W rows d..d+3 are 12 consecutive floats at float4-offset j*192+lane*3.
    float wv[NCHUNK][12];
    const float4* W4 = (const float4*)W;
    #pragma unroll
    for (int j = 0; j < NCHUNK; ++j) {
        #pragma unroll
        for (int q = 0; q < 3; ++q) {
            float4 t = W4[j * 192 + lane * 3 + q];
            wv[j][q * 4 + 0] = t.x;
            wv[j][q * 4 + 1] = t.y;
            wv[j][q * 4 + 2] = t.z;
            wv[j][q * 4 + 3] = t.w;
        }
    }
    const float b0 = bias[0], b1 = bias[1], b2 = bias[2];

    // P in log2-space (float): P ~ 3.5e-21 for steps=50; cheap transcendentals
    // instead of R1's 50 dependent f64 divides.
    int steps = steps_p[0];
    if (steps <= 0 || steps > (1 << 20)) {
        float fs = __int_as_float(steps);
        steps = (fs >= 1.0f && fs < 1.0e6f) ? (int)(fs + 0.5f) : 50;
    }
    const int nt = steps < 2048 ? steps : 2048;
    float logp = 0.f;
    const float ls = __log2f((float)steps);
    for (int t = 1; t <= nt; ++t) logp += __log2f((float)t) - ls;
    const float P   = exp2f(logp);
    const float omP = 1.0f - P;

    const float4* L4 = (const float4*)latent;

    for (int base = wid * RPW; base < rows; base += nwaves * RPW) {
        // ---- issue all 16 loads (4 rows x 4 chunks, 1 KiB per wave-load) ----
        float4 v[RPW][NCHUNK];
        #pragma unroll
        for (int r = 0; r < RPW; ++r) {
            const int row = base + r;
            if (row < rows) {
                const size_t rb = (size_t)row * (D_DIM / 4);
                #pragma unroll
                for (int j = 0; j < NCHUNK; ++j)
                    v[r][j] = L4[rb + j * 64 + lane];
            } else {
                #pragma unroll
                for (int j = 0; j < NCHUNK; ++j)
                    v[r][j] = make_float4(0.f, 0.f, 0.f, 0.f);
            }
        }

        // ---- 12 independent FMA chains ----
        float acc[RPW][3];
        #pragma unroll
        for (int r = 0; r < RPW; ++r) {
            float a0 = 0.f, a1 = 0.f, a2 = 0.f;
            #pragma unroll
            for (int j = 0; j < NCHUNK; ++j) {
                const float4 t = v[r][j];
                a0 = fmaf(t.x, wv[j][0], a0);
                a1 = fmaf(t.x, wv[j][1], a1);
                a2 = fmaf(t.x, wv[j][2], a2);
                a0 = fmaf(t.y, wv[j][3], a0);
                a1 = fmaf(t.y, wv[j][4], a1);
                a2 = fmaf(t.y, wv[j][5], a2);
                a0 = fmaf(t.z, wv[j][6], a0);
                a1 = fmaf(t.z, wv[j][7], a1);
                a2 = fmaf(t.z, wv[j][8], a2);
                a0 = fmaf(t.w, wv[j][9], a0);
                a1 = fmaf(t.w, wv[j][10], a1);
                a2 = fmaf(t.w, wv[j][11], a2);
            }
            acc[r][0] = a0; acc[r][1] = a1; acc[r][2] = a2;
        }

        // ---- butterfly allreduce, 12 independent 6-deep chains ----
        #pragma unroll
        for (int off = 32; off > 0; off >>= 1) {
            #pragma unroll
            for (int r = 0; r < RPW; ++r) {
                acc[r][0] += __shfl_xor(acc[r][0], off, 64);
                acc[r][1] += __shfl_xor(acc[r][1], off, 64);
                acc[r][2] += __shfl_xor(acc[r][2], off, 64);
            }
        }

        // ---- lanes 0..3 store rows base..base+3: 48 contiguous bytes ----
        if (lane < RPW) {
            const int row = base + lane;
            if (row < rows) {
                // static-index select of this lane's row accumulators
                const float s0 = lane == 0 ? acc[0][0] : lane == 1 ? acc[1][0]
                               : lane == 2 ? acc[2][0] : acc[3][0];
                const float s1 = lane == 0 ? acc[0][1] : lane == 1 ? acc[1][1]
                               : lane == 2 ? acc[2][1] : acc[3][1];
                const float s2 = lane == 0 ? acc[0][2] : lane == 1 ? acc[1][2]
                               : lane == 2 ? acc[2][2] : acc[3][2];
                const size_t o = (size_t)row * 3;
                out[o + 0] = omP * (s0 + b0) + P * noise[o + 0];
                out[o + 1] = omP * (s1 + b1) + P * noise[o + 1];
                out[o + 2] = omP * (s2 + b2) + P * noise[o + 2];
            }
        }
    }
}

extern "C" void kernel_launch(void* const* d_in, const int* in_sizes, int n_in,
                              void* d_out, int out_size, void* d_ws, size_t ws_size,
                              hipStream_t stream) {
    const float* latent = (const float*)d_in[0];
    const float* W      = (const float*)d_in[1];
    const float* bias   = (const float*)d_in[2];
    const float* noise  = (const float*)d_in[3];
    const int*   steps  = (const int*)d_in[4];
    float* out = (float*)d_out;

    const int rows = in_sizes[3] / 3;  // B*S = 32768

    // 16 rows per block (4 waves x 4 rows) -> 2048 blocks, one pass, no tail.
    const int blocks = (rows + (RPW * 4) - 1) / (RPW * 4);
    diffusion_init_kernel<<<blocks, 256, 0, stream>>>(latent, W, bias, noise,
                                                      steps, out, rows);
}

// Round 4
// 26.316 us; speedup vs baseline: 1.2281x; 1.1967x over previous
//
#include <hip/hip_runtime.h>

// DiffusionInitializer: out = P*noise + (1-P)*(latent @ W + b), P = prod(t/steps)
// Closed form of the 50-step scan (convex combos; weights sum to 1;
// P = steps!/steps^steps ~ 3.5e-21).
//
// R2 post-mortem: exact-fit grid -> one iteration per wave -> burst/idle duty
// cycle (loads, then compute with memory pipe idle, then relaunch bubble).
// R3/R4: persistent waves (1024 blocks, 8 iters/wave), register double-buffer
// prefetch (next row's 4x16B loads issued before current row's reduce),
// ~100 VGPR -> 4 waves/SIMD occupancy, nontemporal latent loads (read-once
// stream, spare the L2). R4 fixes the compile error: nontemporal builtin
// needs a clang ext_vector_type, not HIP's float4 struct.

#define D_DIM 1024
#define NCHUNK (D_DIM / 256)   // 4 vec4-chunks of 64 lanes each per row

typedef float floatx4 __attribute__((ext_vector_type(4)));

__launch_bounds__(256, 4)
__global__ void diffusion_init_kernel(const float* __restrict__ latent,
                                      const float* __restrict__ W,
                                      const float* __restrict__ bias,
                                      const float* __restrict__ noise,
                                      const int* __restrict__ steps_p,
                                      float* __restrict__ out,
                                      int rows) {
    const int lane   = threadIdx.x & 63;
    const int wid    = (blockIdx.x * blockDim.x + threadIdx.x) >> 6;
    const int nwaves = (gridDim.x * blockDim.x) >> 6;

    // Per-lane W fragment: chunk j covers d = j*256 + lane*4 + k, cols 0..2.
    // W rows d..d+3 = 12 consecutive floats at vec4-offset j*192 + lane*3.
    float wv[NCHUNK][12];
    const floatx4* W4 = (const floatx4*)W;
    #pragma unroll
    for (int j = 0; j < NCHUNK; ++j) {
        #pragma unroll
        for (int q = 0; q < 3; ++q) {
            floatx4 t = W4[j * 192 + lane * 3 + q];
            wv[j][q * 4 + 0] = t.x;
            wv[j][q * 4 + 1] = t.y;
            wv[j][q * 4 + 2] = t.z;
            wv[j][q * 4 + 3] = t.w;
        }
    }
    const float b0 = bias[0], b1 = bias[1], b2 = bias[2];

    // P in log2-space (P ~ 3.5e-21 at steps=50): cheap transcendentals.
    int steps = steps_p[0];
    if (steps <= 0 || steps > (1 << 20)) {
        float fs = __int_as_float(steps);
        steps = (fs >= 1.0f && fs < 1.0e6f) ? (int)(fs + 0.5f) : 50;
    }
    const int nt = steps < 2048 ? steps : 2048;
    float logp = 0.f;
    const float ls = __log2f((float)steps);
    for (int t = 1; t <= nt; ++t) logp += __log2f((float)t) - ls;
    const float P   = exp2f(logp);
    const float omP = 1.0f - P;

    const floatx4* L4 = (const floatx4*)latent;

    int row = wid;
    floatx4 cur[NCHUNK];
    if (row < rows) {
        const size_t rb = (size_t)row * (D_DIM / 4);
        #pragma unroll
        for (int j = 0; j < NCHUNK; ++j)
            cur[j] = __builtin_nontemporal_load(&L4[rb + j * 64 + lane]);
    }

    for (; row < rows; row += nwaves) {
        // ---- prefetch next row (stays in flight through compute/reduce) ----
        floatx4 nxt[NCHUNK];
        const int nrow = row + nwaves;
        if (nrow < rows) {
            const size_t nb = (size_t)nrow * (D_DIM / 4);
            #pragma unroll
            for (int j = 0; j < NCHUNK; ++j)
                nxt[j] = __builtin_nontemporal_load(&L4[nb + j * 64 + lane]);
        } else {
            #pragma unroll
            for (int j = 0; j < NCHUNK; ++j) nxt[j] = (floatx4)(0.f);
        }

        // ---- lane 0 pre-loads this row's noise (hides under the reduce) ----
        float n0 = 0.f, n1 = 0.f, n2 = 0.f;
        const size_t o = (size_t)row * 3;
        if (lane == 0) { n0 = noise[o]; n1 = noise[o + 1]; n2 = noise[o + 2]; }

        // ---- 3 FMA chains over this row's 16 d-values ----
        float a0 = 0.f, a1 = 0.f, a2 = 0.f;
        #pragma unroll
        for (int j = 0; j < NCHUNK; ++j) {
            const floatx4 t = cur[j];
            a0 = fmaf(t.x, wv[j][0], a0);
            a1 = fmaf(t.x, wv[j][1], a1);
            a2 = fmaf(t.x, wv[j][2], a2);
            a0 = fmaf(t.y, wv[j][3], a0);
            a1 = fmaf(t.y, wv[j][4], a1);
            a2 = fmaf(t.y, wv[j][5], a2);
            a0 = fmaf(t.z, wv[j][6], a0);
            a1 = fmaf(t.z, wv[j][7], a1);
            a2 = fmaf(t.z, wv[j][8], a2);
            a0 = fmaf(t.w, wv[j][9], a0);
            a1 = fmaf(t.w, wv[j][10], a1);
            a2 = fmaf(t.w, wv[j][11], a2);
        }

        // ---- 64-lane butterfly allreduce (3 independent 6-deep chains) ----
        #pragma unroll
        for (int off = 32; off > 0; off >>= 1) {
            a0 += __shfl_xor(a0, off, 64);
            a1 += __shfl_xor(a1, off, 64);
            a2 += __shfl_xor(a2, off, 64);
        }

        if (lane == 0) {
            out[o + 0] = omP * (a0 + b0) + P * n0;
            out[o + 1] = omP * (a1 + b1) + P * n1;
            out[o + 2] = omP * (a2 + b2) + P * n2;
        }

        #pragma unroll
        for (int j = 0; j < NCHUNK; ++j) cur[j] = nxt[j];
    }
}

extern "C" void kernel_launch(void* const* d_in, const int* in_sizes, int n_in,
                              void* d_out, int out_size, void* d_ws, size_t ws_size,
                              hipStream_t stream) {
    const float* latent = (const float*)d_in[0];
    const float* W      = (const float*)d_in[1];
    const float* bias   = (const float*)d_in[2];
    const float* noise  = (const float*)d_in[3];
    const int*   steps  = (const int*)d_in[4];
    float* out = (float*)d_out;

    const int rows = in_sizes[3] / 3;  // B*S = 32768

    // 1024 blocks = 4 blocks/CU = 16 waves/CU (full residency at 4 waves/SIMD);
    // 4096 waves -> 8 pipelined grid-stride iterations per wave.
    const int blocks = 1024;
    diffusion_init_kernel<<<blocks, 256, 0, stream>>>(latent, W, bias, noise,
                                                      steps, out, rows);
}